// Round 5
// baseline (1546.469 us; speedup 1.0000x reference)
//
#include <hip/hip_runtime.h>
#include <math.h>

#define DIM_K 7168
#define NE 256
#define NG 8
#define GSZ 32
#define TOPKN 8
#define TOPKG 4

constexpr int BM = 32;      // tokens per block
constexpr int BK = 16;      // k-chunk
constexpr int NCH = DIM_K / BK;  // 448 chunks
constexpr int LDK = BK + 4; // LDS row stride (f32): 20 keeps float4 16B-alignment
                            // (80B rows) and gives <=2-way banks on b128 reads
                            // (20*l15 mod 32 has period 8 -> lane pairs only)

typedef __attribute__((ext_vector_type(4))) double dbl4;

// LDS: GEMM phase uses TWO buffers of (As[BM][LDK] + Bs[NE][LDK]) = 2*23040 B.
// Route phase (after final barrier, GEMM buffers dead) reuses the bytes as
// sc[BM][NE+1] + bsh[NE] = 33920 B.
constexpr int ABYTES = BM * LDK * 4;          // 2560
constexpr int BBYTES = NE * LDK * 4;          // 20480
constexpr int BUFB   = ABYTES + BBYTES;       // 23040 per buffer
constexpr int GEMM_BYTES  = 2 * BUFB;         // 46080
constexpr int ROUTE_BYTES = (BM * (NE + 1) + NE) * 4;  // 33920
constexpr int SMEM_BYTES  = ROUTE_BYTES > GEMM_BYTES ? ROUTE_BYTES : GEMM_BYTES;

// ---------------------------------------------------------------------------
// Fused GEMM + sigmoid + routing. f64-accumulated logits on the f64 matrix
// pipe, f64 sigmoid, RNE cast to f32 (numerics == passing R2/R3/R4 kernels up
// to ~1e-16 f64 re-association).
//
// FRAGMENT LAYOUTS for v_mfma_f64_16x16x4_f64:
//   A[i][k]: i = lane&15, k = lane>>4
//   B[k][j]: j = lane&15, k = lane>>4
//   C/D[i][j]: j = lane&15, i = 4*reg + (lane>>4)   <-- REGISTER-MAJOR (f64
//   quirk, verified R2; standard 16x16 mapping is 4*(lane>>4)+reg).
//
// k-slot remap for VECTOR fragment reads (R5 change): mfma call #s uses
// k_global = 4*lk + s (lane group lk supplies its own contiguous k-quad)
// instead of k_global = 4*s + lk. Each lane then reads its 4 k-values as ONE
// ds_read_b128 (float4) per fragment row: 6 b128/wave/chunk vs 24 b32. Every
// k in [0,16) is still covered exactly once and A/B agree on k per slot, so
// the result differs only by f64 addition order (~1e-16), far below the f32
// score ulp that routing consumes.
// ---------------------------------------------------------------------------
__global__ __launch_bounds__(256, 2)
void gemm_sigmoid_route(const float* __restrict__ x,
                        const float* __restrict__ w,
                        const float* __restrict__ bias,
                        float* __restrict__ out_w,
                        float* __restrict__ out_i)
{
    __shared__ __align__(16) char smem[SMEM_BYTES];

    const int tid  = threadIdx.x;
    const int wave = tid >> 6;
    const int lane = tid & 63;
    const int m_blk = blockIdx.x * BM;

    const int l15 = lane & 15;
    const int lk  = lane >> 4;        // lane's k-group / row sub-idx
    const int klo = lk * 4;           // contiguous k-quad base for this lane
    const int e_base = wave * 64;     // wave's 64-expert slice

    const dbl4 zero = {0.0, 0.0, 0.0, 0.0};
    dbl4 acc[2][4];                   // [m-subtile][e-subtile], 64 VGPRs
#pragma unroll
    for (int i = 0; i < 2; ++i)
#pragma unroll
        for (int j = 0; j < 4; ++j) acc[i][j] = zero;

    // staging: A 32x16 f32 (128 float4, threads<128) + B 256x16 f32 (4 float4
    // per thread). Row-major in LDS -> float4 load + b128 write, no transpose.
    const int srow = tid >> 2;        // 0..63
    const int sc4  = (tid & 3) * 4;   // f32 col within chunk

    const float* xa = x + (long)(m_blk + (srow & 31)) * DIM_K + sc4;
    const float* wb = w + (long)srow * DIM_K + sc4;

    float (*Ar)[LDK] = (float (*)[LDK])(smem);                  // read buf
    float (*Br)[LDK] = (float (*)[LDK])(smem + ABYTES);
    float (*Aw)[LDK] = (float (*)[LDK])(smem + BUFB);           // write buf
    float (*Bw)[LDK] = (float (*)[LDK])(smem + BUFB + ABYTES);

    float4 ra, rb0, rb1, rb2, rb3;

    // prologue: chunk 0 -> regs -> buf0; chunk 1 -> regs; barrier.
    if (tid < 128) ra = *(const float4*)xa;
    rb0 = *(const float4*)(wb);
    rb1 = *(const float4*)(wb + (long) 64 * DIM_K);
    rb2 = *(const float4*)(wb + (long)128 * DIM_K);
    rb3 = *(const float4*)(wb + (long)192 * DIM_K);
    if (tid < 128) *(float4*)&Ar[srow & 31][sc4] = ra;
    *(float4*)&Br[srow      ][sc4] = rb0;
    *(float4*)&Br[srow +  64][sc4] = rb1;
    *(float4*)&Br[srow + 128][sc4] = rb2;
    *(float4*)&Br[srow + 192][sc4] = rb3;
    if (tid < 128) ra = *(const float4*)(xa + BK);
    rb0 = *(const float4*)(wb + BK);
    rb1 = *(const float4*)(wb + BK + (long) 64 * DIM_K);
    rb2 = *(const float4*)(wb + BK + (long)128 * DIM_K);
    rb3 = *(const float4*)(wb + BK + (long)192 * DIM_K);
    __syncthreads();

    for (int t = 0; t < NCH; ++t) {
        // stage chunk t+1 (regs loaded an iteration ago, long landed) into the
        // buffer nobody reads this iteration; then issue loads for chunk t+2 —
        // their latency hides under the MFMA cluster below (T3 recipe order).
        if (t + 1 < NCH) {
            if (tid < 128) *(float4*)&Aw[srow & 31][sc4] = ra;
            *(float4*)&Bw[srow      ][sc4] = rb0;
            *(float4*)&Bw[srow +  64][sc4] = rb1;
            *(float4*)&Bw[srow + 128][sc4] = rb2;
            *(float4*)&Bw[srow + 192][sc4] = rb3;
            if (t + 2 < NCH) {
                const int off = (t + 2) * BK;
                if (tid < 128) ra = *(const float4*)(xa + off);
                rb0 = *(const float4*)(wb + off);
                rb1 = *(const float4*)(wb + off + (long) 64 * DIM_K);
                rb2 = *(const float4*)(wb + off + (long)128 * DIM_K);
                rb3 = *(const float4*)(wb + off + (long)192 * DIM_K);
            }
        }

        // MFMA cluster: 6 x ds_read_b128 fragment loads, then 4 mfma steps.
        {
            const float4 a4_0 = *(const float4*)&Ar[l15     ][klo];
            const float4 a4_1 = *(const float4*)&Ar[l15 + 16][klo];
            const float4 b4_0 = *(const float4*)&Br[e_base      + l15][klo];
            const float4 b4_1 = *(const float4*)&Br[e_base + 16 + l15][klo];
            const float4 b4_2 = *(const float4*)&Br[e_base + 32 + l15][klo];
            const float4 b4_3 = *(const float4*)&Br[e_base + 48 + l15][klo];
            const float a0f[4] = {a4_0.x, a4_0.y, a4_0.z, a4_0.w};
            const float a1f[4] = {a4_1.x, a4_1.y, a4_1.z, a4_1.w};
            const float b0f[4] = {b4_0.x, b4_0.y, b4_0.z, b4_0.w};
            const float b1f[4] = {b4_1.x, b4_1.y, b4_1.z, b4_1.w};
            const float b2f[4] = {b4_2.x, b4_2.y, b4_2.z, b4_2.w};
            const float b3f[4] = {b4_3.x, b4_3.y, b4_3.z, b4_3.w};
#pragma unroll
            for (int s = 0; s < 4; ++s) {
                const double a0 = (double)a0f[s];
                const double a1 = (double)a1f[s];
                const double b0 = (double)b0f[s];
                const double b1 = (double)b1f[s];
                const double b2 = (double)b2f[s];
                const double b3 = (double)b3f[s];
                acc[0][0] = __builtin_amdgcn_mfma_f64_16x16x4f64(a0, b0, acc[0][0], 0, 0, 0);
                acc[1][0] = __builtin_amdgcn_mfma_f64_16x16x4f64(a1, b0, acc[1][0], 0, 0, 0);
                acc[0][1] = __builtin_amdgcn_mfma_f64_16x16x4f64(a0, b1, acc[0][1], 0, 0, 0);
                acc[1][1] = __builtin_amdgcn_mfma_f64_16x16x4f64(a1, b1, acc[1][1], 0, 0, 0);
                acc[0][2] = __builtin_amdgcn_mfma_f64_16x16x4f64(a0, b2, acc[0][2], 0, 0, 0);
                acc[1][2] = __builtin_amdgcn_mfma_f64_16x16x4f64(a1, b2, acc[1][2], 0, 0, 0);
                acc[0][3] = __builtin_amdgcn_mfma_f64_16x16x4f64(a0, b3, acc[0][3], 0, 0, 0);
                acc[1][3] = __builtin_amdgcn_mfma_f64_16x16x4f64(a1, b3, acc[1][3], 0, 0, 0);
            }
        }
        __syncthreads();

        // swap read/write buffers
        float (*tp)[LDK];
        tp = Ar; Ar = Aw; Aw = tp;
        tp = Br; Br = Bw; Bw = tp;
    }
    // All GEMM buffers dead -> repurpose LDS for routing.

    float (*sc)[NE + 1] = (float (*)[NE + 1])smem;                // [BM][257]
    float* bsh = (float*)(smem + BM * (NE + 1) * 4);              // [NE]

    // f64 sigmoid, RNE cast to f32, scattered to LDS score rows.
    // f64-MFMA C/D row mapping: row = 4*reg + (lane>>4)  (register-major).
#pragma unroll
    for (int mi = 0; mi < 2; ++mi) {
#pragma unroll
        for (int j = 0; j < 4; ++j) {
#pragma unroll
            for (int r = 0; r < 4; ++r) {
                const int m = mi * 16 + r * 4 + lk;
                const int e = e_base + j * 16 + l15;
                sc[m][e] = (float)(1.0 / (1.0 + exp(-acc[mi][j][r])));
            }
        }
    }
    if (tid < 64) {
        const float4 bv = *(const float4*)(bias + tid * 4);
        bsh[tid * 4 + 0] = bv.x;
        bsh[tid * 4 + 1] = bv.y;
        bsh[tid * 4 + 2] = bv.z;
        bsh[tid * 4 + 3] = bv.w;
    }
    __syncthreads();

    // np-faithful f32 routing, one thread per token (threads 0..31).
    // Identical scan order / __fadd_rn semantics to the passing route_f32.
    if (tid < BM) {
        float* row = sc[tid];

        // group score = top-2 sum of biased scores (f32 add, m1+m2 order = np)
        float gs[NG];
#pragma unroll
        for (int g = 0; g < NG; ++g) {
            float m1 = -3.0e38f, m2 = -3.0e38f;
            for (int j = 0; j < GSZ; ++j) {
                const int e = g * GSZ + j;
                const float v = __fadd_rn(row[e], bsh[e]);
                if (v > m1) { m2 = m1; m1 = v; }
                else if (v > m2) { m2 = v; }
            }
            gs[g] = __fadd_rn(m1, m2);
        }

        // top-4 groups (selection set only)
        unsigned keep = 0;
#pragma unroll
        for (int r = 0; r < TOPKG; ++r) {
            float best = -3.0e38f; int bg = 0;
            for (int g = 0; g < NG; ++g)
                if (!((keep >> g) & 1u) && gs[g] > best) { best = gs[g]; bg = g; }
            keep |= 1u << bg;
        }

        // top-8 experts over kept groups by biased f32 score
        float wv[TOPKN]; int iv[TOPKN];
        for (int r = 0; r < TOPKN; ++r) {
            float best = -3.0e38f; int bi = 0;
            for (int g = 0; g < NG; ++g) {
                if (!((keep >> g) & 1u)) continue;
                for (int j = 0; j < GSZ; ++j) {
                    const int e = g * GSZ + j;
                    const float v = __fadd_rn(row[e], bsh[e]);
                    if (v > best) { best = v; bi = e; }
                }
            }
            wv[r] = row[bi];        // ORIGINAL (un-biased) f32 sigmoid score
            iv[r] = bi;
            row[bi] = -3.0e38f;     // -3e38 + bias stays -3e38; never re-picked
        }

        // np n=8 pairwise-sum tree, then div-then-mul (elementwise, f32)
        const float s01 = __fadd_rn(wv[0], wv[1]);
        const float s23 = __fadd_rn(wv[2], wv[3]);
        const float s45 = __fadd_rn(wv[4], wv[5]);
        const float s67 = __fadd_rn(wv[6], wv[7]);
        const float wsum = __fadd_rn(__fadd_rn(s01, s23), __fadd_rn(s45, s67));

        const long token = m_blk + tid;
#pragma unroll
        for (int r = 0; r < TOPKN; ++r) {
            out_w[token * 8 + r] = __fmul_rn(__fdiv_rn(wv[r], wsum), 2.5f);
            out_i[token * 8 + r] = (float)iv[r];
        }
    }
}

extern "C" void kernel_launch(void* const* d_in, const int* in_sizes, int n_in,
                              void* d_out, int out_size, void* d_ws, size_t ws_size,
                              hipStream_t stream)
{
    const float* x    = (const float*)d_in[0];
    const float* w    = (const float*)d_in[1];
    const float* bias = (const float*)d_in[2];
    float* out = (float*)d_out;
    const int T = in_sizes[0] / DIM_K;      // 16384

    gemm_sigmoid_route<<<dim3(T / BM), dim3(256), 0, stream>>>(
        x, w, bias, out, out + (long)T * TOPKN);
}

// Round 6
// 1440.249 us; speedup vs baseline: 1.0738x; 1.0738x over previous
//
#include <hip/hip_runtime.h>
#include <math.h>

#define DIM_K 7168
#define NE 256
#define NG 8
#define GSZ 32
#define TOPKN 8
#define TOPKG 4

constexpr int BM = 32;      // tokens per block
constexpr int BK = 16;      // k-chunk
constexpr int NCH = DIM_K / BK;  // 448 chunks

typedef __attribute__((ext_vector_type(4))) double dbl4;

// LDS is used ONLY by the route phase now: sc[BM][NE+1] + bsh[NE] = 33920 B.
constexpr int ROUTE_BYTES = (BM * (NE + 1) + NE) * 4;

// ---------------------------------------------------------------------------
// Fused GEMM + sigmoid + routing, ZERO-LDS / ZERO-BARRIER k-loop.
//
// R4 (explicit dbuf) and R5 (vectorized LDS fragment reads) were both NULL:
// the 2-barrier lockstep chunk structure itself is the ~2170 cyc/chunk/SIMD
// bubble. Fix: fragments are per-lane contiguous float4 (thanks to R5's
// k-quad remap), so load them DIRECTLY from global -> no ds_write, no
// ds_read, no __syncthreads in the k-loop. Register double-buffer (load
// chunk t+1 during mfma of chunk t); waves drift freely, matrix pipe stays
// fed. Bandwidth: ~5 B/cyc/CU needed vs 56 B/cyc L2 ceiling; W (7.3MB) is
// L2/L3-resident, A is L1-hot (4 waves read identical addresses).
//
// Numerics IDENTICAL to passed R5: same k-slot assignment (call s uses
// k_global = 4*lk + s), same f64 accumulation order, f64 sigmoid, RNE->f32.
//
// FRAGMENT LAYOUTS for v_mfma_f64_16x16x4_f64:
//   A[i][k]: i = lane&15, k = lane>>4
//   B[k][j]: j = lane&15, k = lane>>4
//   C/D[i][j]: j = lane&15, i = 4*reg + (lane>>4)   <-- REGISTER-MAJOR (f64
//   quirk, verified R2; standard 16x16 mapping is 4*(lane>>4)+reg).
// ---------------------------------------------------------------------------

#define MFMA_CLUSTER(A0, A1, B0, B1, B2, B3)                                   \
    do {                                                                       \
        const float af0[4] = {(A0).x, (A0).y, (A0).z, (A0).w};                 \
        const float af1[4] = {(A1).x, (A1).y, (A1).z, (A1).w};                 \
        const float bf0[4] = {(B0).x, (B0).y, (B0).z, (B0).w};                 \
        const float bf1[4] = {(B1).x, (B1).y, (B1).z, (B1).w};                 \
        const float bf2[4] = {(B2).x, (B2).y, (B2).z, (B2).w};                 \
        const float bf3[4] = {(B3).x, (B3).y, (B3).z, (B3).w};                 \
        _Pragma("unroll")                                                      \
        for (int s = 0; s < 4; ++s) {                                          \
            const double a0 = (double)af0[s];                                  \
            const double a1 = (double)af1[s];                                  \
            const double b0 = (double)bf0[s];                                  \
            const double b1 = (double)bf1[s];                                  \
            const double b2 = (double)bf2[s];                                  \
            const double b3 = (double)bf3[s];                                  \
            acc[0][0] = __builtin_amdgcn_mfma_f64_16x16x4f64(a0, b0, acc[0][0], 0, 0, 0); \
            acc[1][0] = __builtin_amdgcn_mfma_f64_16x16x4f64(a1, b0, acc[1][0], 0, 0, 0); \
            acc[0][1] = __builtin_amdgcn_mfma_f64_16x16x4f64(a0, b1, acc[0][1], 0, 0, 0); \
            acc[1][1] = __builtin_amdgcn_mfma_f64_16x16x4f64(a1, b1, acc[1][1], 0, 0, 0); \
            acc[0][2] = __builtin_amdgcn_mfma_f64_16x16x4f64(a0, b2, acc[0][2], 0, 0, 0); \
            acc[1][2] = __builtin_amdgcn_mfma_f64_16x16x4f64(a1, b2, acc[1][2], 0, 0, 0); \
            acc[0][3] = __builtin_amdgcn_mfma_f64_16x16x4f64(a0, b3, acc[0][3], 0, 0, 0); \
            acc[1][3] = __builtin_amdgcn_mfma_f64_16x16x4f64(a1, b3, acc[1][3], 0, 0, 0); \
        }                                                                      \
    } while (0)

__global__ __launch_bounds__(256, 2)
void gemm_sigmoid_route(const float* __restrict__ x,
                        const float* __restrict__ w,
                        const float* __restrict__ bias,
                        float* __restrict__ out_w,
                        float* __restrict__ out_i)
{
    __shared__ __align__(16) char smem[ROUTE_BYTES];

    const int tid  = threadIdx.x;
    const int wave = tid >> 6;
    const int lane = tid & 63;
    const int m_blk = blockIdx.x * BM;

    const int l15 = lane & 15;
    const int lk  = lane >> 4;        // lane's k-group / row sub-idx
    const int klo = lk * 4;           // contiguous k-quad base for this lane
    const int e_base = wave * 64;     // wave's 64-expert slice

    const dbl4 zero = {0.0, 0.0, 0.0, 0.0};
    dbl4 acc[2][4];                   // [m-subtile][e-subtile], 64 VGPRs
#pragma unroll
    for (int i = 0; i < 2; ++i)
#pragma unroll
        for (int j = 0; j < 4; ++j) acc[i][j] = zero;

    // Per-lane fragment base pointers (advance by BK floats per chunk).
    const float* pa0 = x + (long)(m_blk + l15     ) * DIM_K + klo;
    const float* pa1 = x + (long)(m_blk + 16 + l15) * DIM_K + klo;
    const float* pb0 = w + (long)(e_base      + l15) * DIM_K + klo;
    const float* pb1 = pb0 + (long)16 * DIM_K;
    const float* pb2 = pb0 + (long)32 * DIM_K;
    const float* pb3 = pb0 + (long)48 * DIM_K;

    // chunk 0 -> current regs
    float4 a0c = *(const float4*)pa0;
    float4 a1c = *(const float4*)pa1;
    float4 b0c = *(const float4*)pb0;
    float4 b1c = *(const float4*)pb1;
    float4 b2c = *(const float4*)pb2;
    float4 b3c = *(const float4*)pb3;

    for (int t = 0; t < NCH - 1; ++t) {
        const int off = (t + 1) * BK;
        // issue chunk t+1 loads; latency hides under the 32 mfma below
        const float4 a0n = *(const float4*)(pa0 + off);
        const float4 a1n = *(const float4*)(pa1 + off);
        const float4 b0n = *(const float4*)(pb0 + off);
        const float4 b1n = *(const float4*)(pb1 + off);
        const float4 b2n = *(const float4*)(pb2 + off);
        const float4 b3n = *(const float4*)(pb3 + off);

        MFMA_CLUSTER(a0c, a1c, b0c, b1c, b2c, b3c);

        a0c = a0n; a1c = a1n;
        b0c = b0n; b1c = b1n; b2c = b2n; b3c = b3n;
    }
    MFMA_CLUSTER(a0c, a1c, b0c, b1c, b2c, b3c);   // last chunk

    // ---- route phase (unchanged from passing R3/R4/R5) ----
    float (*sc)[NE + 1] = (float (*)[NE + 1])smem;                // [BM][257]
    float* bsh = (float*)(smem + BM * (NE + 1) * 4);              // [NE]

    // f64 sigmoid, RNE cast to f32, scattered to LDS score rows.
    // f64-MFMA C/D row mapping: row = 4*reg + (lane>>4)  (register-major).
#pragma unroll
    for (int mi = 0; mi < 2; ++mi) {
#pragma unroll
        for (int j = 0; j < 4; ++j) {
#pragma unroll
            for (int r = 0; r < 4; ++r) {
                const int m = mi * 16 + r * 4 + lk;
                const int e = e_base + j * 16 + l15;
                sc[m][e] = (float)(1.0 / (1.0 + exp(-acc[mi][j][r])));
            }
        }
    }
    if (tid < 64) {
        const float4 bv = *(const float4*)(bias + tid * 4);
        bsh[tid * 4 + 0] = bv.x;
        bsh[tid * 4 + 1] = bv.y;
        bsh[tid * 4 + 2] = bv.z;
        bsh[tid * 4 + 3] = bv.w;
    }
    __syncthreads();

    // np-faithful f32 routing, one thread per token (threads 0..31).
    if (tid < BM) {
        float* row = sc[tid];

        // group score = top-2 sum of biased scores (f32 add, m1+m2 order = np)
        float gs[NG];
#pragma unroll
        for (int g = 0; g < NG; ++g) {
            float m1 = -3.0e38f, m2 = -3.0e38f;
            for (int j = 0; j < GSZ; ++j) {
                const int e = g * GSZ + j;
                const float v = __fadd_rn(row[e], bsh[e]);
                if (v > m1) { m2 = m1; m1 = v; }
                else if (v > m2) { m2 = v; }
            }
            gs[g] = __fadd_rn(m1, m2);
        }

        // top-4 groups (selection set only)
        unsigned keep = 0;
#pragma unroll
        for (int r = 0; r < TOPKG; ++r) {
            float best = -3.0e38f; int bg = 0;
            for (int g = 0; g < NG; ++g)
                if (!((keep >> g) & 1u) && gs[g] > best) { best = gs[g]; bg = g; }
            keep |= 1u << bg;
        }

        // top-8 experts over kept groups by biased f32 score
        float wv[TOPKN]; int iv[TOPKN];
        for (int r = 0; r < TOPKN; ++r) {
            float best = -3.0e38f; int bi = 0;
            for (int g = 0; g < NG; ++g) {
                if (!((keep >> g) & 1u)) continue;
                for (int j = 0; j < GSZ; ++j) {
                    const int e = g * GSZ + j;
                    const float v = __fadd_rn(row[e], bsh[e]);
                    if (v > best) { best = v; bi = e; }
                }
            }
            wv[r] = row[bi];        // ORIGINAL (un-biased) f32 sigmoid score
            iv[r] = bi;
            row[bi] = -3.0e38f;     // -3e38 + bias stays -3e38; never re-picked
        }

        // np n=8 pairwise-sum tree, then div-then-mul (elementwise, f32)
        const float s01 = __fadd_rn(wv[0], wv[1]);
        const float s23 = __fadd_rn(wv[2], wv[3]);
        const float s45 = __fadd_rn(wv[4], wv[5]);
        const float s67 = __fadd_rn(wv[6], wv[7]);
        const float wsum = __fadd_rn(__fadd_rn(s01, s23), __fadd_rn(s45, s67));

        const long token = m_blk + tid;
#pragma unroll
        for (int r = 0; r < TOPKN; ++r) {
            out_w[token * 8 + r] = __fmul_rn(__fdiv_rn(wv[r], wsum), 2.5f);
            out_i[token * 8 + r] = (float)iv[r];
        }
    }
}

extern "C" void kernel_launch(void* const* d_in, const int* in_sizes, int n_in,
                              void* d_out, int out_size, void* d_ws, size_t ws_size,
                              hipStream_t stream)
{
    const float* x    = (const float*)d_in[0];
    const float* w    = (const float*)d_in[1];
    const float* bias = (const float*)d_in[2];
    float* out = (float*)d_out;
    const int T = in_sizes[0] / DIM_K;      // 16384

    gemm_sigmoid_route<<<dim3(T / BM), dim3(256), 0, stream>>>(
        x, w, bias, out, out + (long)T * TOPKN);
}